// Round 4
// baseline (126.630 us; speedup 1.0000x reference)
//
#include <hip/hip_runtime.h>
#include <math.h>

// WaveletLayer: (B=4096, S=50, H=256) fp32.
// Per (b,h): 3-level db3 wavedec (ptwt reflect) -> per-band filter multiply ->
// waverec -> +residual -> LayerNorm over H.
// fp16x2-packed wavelet pipeline (round 2). Round-3 fix: the per-band filter
// loads f[h*L+l] were a 40-lines-per-wave gather (63 instr/thread, ~67us of
// TA serialization per CU). A prep kernel transposes+packs filters into d_ws
// as [l][h]-major f16x2 so the main kernel does ~32 coalesced dword loads.

#define S_LEN 50
#define H_DIM 256
#define NPAIR 25

typedef _Float16 f16;
typedef __attribute__((ext_vector_type(2))) _Float16 f16x2;
typedef __attribute__((ext_vector_type(8))) _Float16 f16x8;

// d_ws layout (f16x2 elements): ft01 [10][256] | ft2 [8][256] | ft3 [14][256]
#define FT01_OFF 0
#define FT2_OFF (10 * H_DIM)
#define FT3_OFF (18 * H_DIM)
#define FT_BYTES (32 * H_DIM * 4)  // 32768

__device__ constexpr float DLO[6] = {
    0.035226291882100656f, -0.08544127388224149f, -0.13501102001039084f,
    0.4598775021193313f,   0.8068915093133388f,   0.3326705529509569f};
__device__ constexpr float DHI[6] = {
    -0.3326705529509569f,  0.8068915093133388f,  -0.4598775021193313f,
    -0.13501102001039084f, 0.08544127388224149f,  0.035226291882100656f};

static __device__ __forceinline__ f16x2 splat2(f16 v) {
  f16x2 r; r.x = v; r.y = v; return r;
}
static __device__ __forceinline__ f16x2 mk2(float a, float b) {
  f16x2 r; r.x = (f16)a; r.y = (f16)b; return r;
}

// Transpose+pack the learned filters into [l][h]-major f16x2 in ws.
__global__ void prep_filters(const float* __restrict__ f0,
                             const float* __restrict__ f1,
                             const float* __restrict__ f2,
                             const float* __restrict__ f3,
                             f16x2* __restrict__ ft) {
  const int h = threadIdx.x;
  const int b = blockIdx.x;
  if (b < 10) {  // (f0, f1) pair at tap l
    const int l = b;
    f16x2 v; v.x = (f16)f0[h * 10 + l]; v.y = (f16)f1[h * 10 + l];
    ft[FT01_OFF + l * H_DIM + h] = v;
  } else if (b < 18) {  // f2 taps (2k, 2k+1)
    const int k = b - 10;
    f16x2 v; v.x = (f16)f2[h * 16 + 2 * k]; v.y = (f16)f2[h * 16 + 2 * k + 1];
    ft[FT2_OFF + k * H_DIM + h] = v;
  } else {  // f3 taps (2k, 2k+1), last pair padded
    const int k = b - 18;
    f16x2 v;
    v.x = (f16)f3[h * 27 + 2 * k];
    v.y = (2 * k + 1 < 27) ? (f16)f3[h * 27 + 2 * k + 1] : (f16)0.f;
    ft[FT3_OFF + k * H_DIM + h] = v;
  }
}

// One analysis level, (lo,hi)-packed. out[i] = {cA[i], cD[i]}.
template <int N, class Get>
__device__ __forceinline__ void dwt_f16(const Get& X, f16x2* out) {
  constexpr int M = (N + 5) / 2;
#pragma unroll
  for (int i = 0; i < M; ++i) {
    f16x2 acc = mk2(0.f, 0.f);
#pragma unroll
    for (int j = 0; j < 6; ++j) {
      int idx = 2 * i + j - 4;
      idx = idx < 0 ? -idx : idx;
      idx = idx >= N ? 2 * N - 2 - idx : idx;
      acc += splat2(X(idx)) * mk2(DLO[5 - j], DHI[5 - j]);
    }
    out[i] = acc;
  }
}

// One synthesis level, adjacent-packed output: out2[t] = {rec[2t], rec[2t+1]}.
template <int T, class GLo, class GHi>
__device__ __forceinline__ void idwt_f16(const GLo& lo, const GHi& hi,
                                         f16x2* out2) {
#pragma unroll
  for (int t = 0; t < T / 2; ++t) {
    f16x2 acc = mk2(0.f, 0.f);
#pragma unroll
    for (int k = 0; k < 3; ++k) {
      acc += splat2(lo(t + k)) * mk2(DLO[2 * k + 1], DLO[2 * k]);
      acc += splat2(hi(t + k)) * mk2(DHI[2 * k + 1], DHI[2 * k]);
    }
    out2[t] = acc;
  }
  if constexpr (T & 1) {  // tail p = T-1 (even): taps {1,3,5}
    constexpr int t0 = T / 2;
    f16 s = (f16)0.f;
#pragma unroll
    for (int k = 0; k < 3; ++k)
      s += lo(t0 + k) * (f16)DLO[2 * k + 1] + hi(t0 + k) * (f16)DHI[2 * k + 1];
    f16x2 r; r.x = s; r.y = (f16)0.f;
    out2[t0] = r;
  }
}

template <bool USE_WS>
__global__ __launch_bounds__(256, 6) void wavelet_ln_kernel(
    const float* __restrict__ in, const float* __restrict__ f0,
    const float* __restrict__ f1, const float* __restrict__ f2,
    const float* __restrict__ f3, const f16x2* __restrict__ ft,
    const float* __restrict__ gam, const float* __restrict__ bet,
    float* __restrict__ out) {
  __shared__ f16x2 slab[NPAIR * H_DIM];  // 25600 B -> 6 blocks/CU
  const int tid = threadIdx.x;
  const size_t base = (size_t)blockIdx.x * (S_LEN * H_DIM);
  const float4* in4 = (const float4*)(in + base);

  // ---- phase 0: stage x as f16 pairs {x[2t],x[2t+1]} per h (float4 loads) --
  {
    f16x8* s8 = (f16x8*)slab;
#pragma unroll
    for (int i = 0; i < 7; ++i) {
      const int idx = i * 256 + tid;  // quad-of-pairs index in [0,1600)
      if (idx < NPAIR * 64) {
        const int t = idx >> 6, hq = idx & 63;
        const float4 a = in4[(2 * t) * 64 + hq];
        const float4 b = in4[(2 * t + 1) * 64 + hq];
        f16x8 o;
        o.s0 = (f16)a.x; o.s1 = (f16)b.x;
        o.s2 = (f16)a.y; o.s3 = (f16)b.y;
        o.s4 = (f16)a.z; o.s5 = (f16)b.z;
        o.s6 = (f16)a.w; o.s7 = (f16)b.w;
        s8[idx] = o;
      }
    }
  }
  __syncthreads();

  const int h = tid;

  // ---- phase 1: packed fp16 wavelet pipeline on own column ----
  {
    f16x2 xp[NPAIR];
#pragma unroll
    for (int t = 0; t < NPAIR; ++t) xp[t] = slab[t * H_DIM + h];  // 2-way, free

    f16x2 AD1[27];
    dwt_f16<50>([&](int s) -> f16 { return (s & 1) ? xp[s >> 1].y
                                                   : xp[s >> 1].x; }, AD1);
    f16x2 AD2[16];
    dwt_f16<27>([&](int s) -> f16 { return AD1[s].x; }, AD2);
    f16x2 AD3[10];
    dwt_f16<16>([&](int s) -> f16 { return AD2[s].x; }, AD3);

    // per-band learned filter multiply
    if constexpr (USE_WS) {
      // coalesced [l][h]-major packed loads (4 lines/wave-instr)
#pragma unroll
      for (int l = 0; l < 10; ++l) AD3[l] *= ft[FT01_OFF + l * H_DIM + h];
#pragma unroll
      for (int k = 0; k < 8; ++k) {
        const f16x2 c = ft[FT2_OFF + k * H_DIM + h];
        AD2[2 * k].y *= c.x;
        AD2[2 * k + 1].y *= c.y;
      }
#pragma unroll
      for (int k = 0; k < 14; ++k) {
        const f16x2 c = ft[FT3_OFF + k * H_DIM + h];
        AD1[2 * k].y *= c.x;
        if (2 * k + 1 < 27) AD1[2 * k + 1].y *= c.y;
      }
    } else {  // fallback: direct (gathered) loads
      const float* f0h = f0 + h * 10;
      const float* f1h = f1 + h * 10;
#pragma unroll
      for (int l = 0; l < 10; ++l) AD3[l] *= mk2(f0h[l], f1h[l]);
      const float* f2h = f2 + h * 16;
#pragma unroll
      for (int l = 0; l < 16; ++l) AD2[l].y *= (f16)f2h[l];
      const float* f3h = f3 + h * 27;
#pragma unroll
      for (int l = 0; l < 27; ++l) AD1[l].y *= (f16)f3h[l];
    }

    // synthesis
    f16x2 rr2[8];
    idwt_f16<16>([&](int s) -> f16 { return AD3[s].x; },
                 [&](int s) -> f16 { return AD3[s].y; }, rr2);
    f16x2 rr1[14];
    idwt_f16<27>([&](int s) -> f16 { return (s & 1) ? rr2[s >> 1].y
                                                    : rr2[s >> 1].x; },
                 [&](int s) -> f16 { return AD2[s].y; }, rr1);

    // final level fused: write rec pairs over the slab (column-private)
    auto lo = [&](int s) -> f16 { return (s & 1) ? rr1[s >> 1].y
                                                 : rr1[s >> 1].x; };
    auto hi = [&](int s) -> f16 { return AD1[s].y; };
#pragma unroll
    for (int t = 0; t < NPAIR; ++t) {
      f16x2 acc = mk2(0.f, 0.f);
#pragma unroll
      for (int k = 0; k < 3; ++k) {
        acc += splat2(lo(t + k)) * mk2(DLO[2 * k + 1], DLO[2 * k]);
        acc += splat2(hi(t + k)) * mk2(DHI[2 * k + 1], DHI[2 * k]);
      }
      slab[t * H_DIM + h] = acc;
    }
  }
  __syncthreads();

  // ---- phase 2: LN over H, two s-rows per iteration per wave ----
  const int lane = tid & 63;
  const int wv = tid >> 6;
  const float4 g4 = ((const float4*)gam)[lane];
  const float4 b4 = ((const float4*)bet)[lane];
  float4* out4 = (float4*)(out + base);
  const f16x8* s8 = (const f16x8*)slab;
  for (int t = wv; t < NPAIR; t += 4) {
    const f16x8 r8 = s8[t * 64 + lane];           // rec pairs, 4 h's
    const float4 xa = in4[(2 * t) * 64 + lane];   // exact x, L2/L3-hit
    const float4 xb = in4[(2 * t + 1) * 64 + lane];
    const float ye0 = xa.x + (float)r8.s0, yo0 = xb.x + (float)r8.s1;
    const float ye1 = xa.y + (float)r8.s2, yo1 = xb.y + (float)r8.s3;
    const float ye2 = xa.z + (float)r8.s4, yo2 = xb.z + (float)r8.s5;
    const float ye3 = xa.w + (float)r8.s6, yo3 = xb.w + (float)r8.s7;
    float se = ye0 + ye1 + ye2 + ye3;
    float so = yo0 + yo1 + yo2 + yo3;
    float qe = ye0 * ye0 + ye1 * ye1 + ye2 * ye2 + ye3 * ye3;
    float qo = yo0 * yo0 + yo1 * yo1 + yo2 * yo2 + yo3 * yo3;
#pragma unroll
    for (int o = 32; o >= 1; o >>= 1) {
      se += __shfl_xor(se, o);
      so += __shfl_xor(so, o);
      qe += __shfl_xor(qe, o);
      qo += __shfl_xor(qo, o);
    }
    const float mue = se * (1.0f / H_DIM), muo = so * (1.0f / H_DIM);
    const float rse =
        rsqrtf(fmaxf(qe * (1.0f / H_DIM) - mue * mue, 0.0f) + 1e-12f);
    const float rso =
        rsqrtf(fmaxf(qo * (1.0f / H_DIM) - muo * muo, 0.0f) + 1e-12f);
    float4 oe, oo;
    oe.x = (ye0 - mue) * rse * g4.x + b4.x;
    oe.y = (ye1 - mue) * rse * g4.y + b4.y;
    oe.z = (ye2 - mue) * rse * g4.z + b4.z;
    oe.w = (ye3 - mue) * rse * g4.w + b4.w;
    oo.x = (yo0 - muo) * rso * g4.x + b4.x;
    oo.y = (yo1 - muo) * rso * g4.y + b4.y;
    oo.z = (yo2 - muo) * rso * g4.z + b4.z;
    oo.w = (yo3 - muo) * rso * g4.w + b4.w;
    out4[(2 * t) * 64 + lane] = oe;       // dense coalesced row stores
    out4[(2 * t + 1) * 64 + lane] = oo;
  }
}

extern "C" void kernel_launch(void* const* d_in, const int* in_sizes, int n_in,
                              void* d_out, int out_size, void* d_ws,
                              size_t ws_size, hipStream_t stream) {
  // setup_inputs() dict order: input_tensor, ln_gamma, ln_beta, filt0..filt3
  const float* in = (const float*)d_in[0];
  const float* gam = (const float*)d_in[1];
  const float* bet = (const float*)d_in[2];
  const float* f0 = (const float*)d_in[3];
  const float* f1 = (const float*)d_in[4];
  const float* f2 = (const float*)d_in[5];
  const float* f3 = (const float*)d_in[6];
  float* out = (float*)d_out;

  if (ws_size >= (size_t)FT_BYTES) {
    f16x2* ft = (f16x2*)d_ws;
    prep_filters<<<32, 256, 0, stream>>>(f0, f1, f2, f3, ft);
    wavelet_ln_kernel<true><<<4096, 256, 0, stream>>>(in, f0, f1, f2, f3, ft,
                                                      gam, bet, out);
  } else {
    wavelet_ln_kernel<false><<<4096, 256, 0, stream>>>(
        in, f0, f1, f2, f3, nullptr, gam, bet, out);
  }
}

// Round 5
// 112.373 us; speedup vs baseline: 1.1269x; 1.1269x over previous
//
#include <hip/hip_runtime.h>
#include <math.h>

// WaveletLayer: (B=4096, S=50, H=256) fp32.
// Per (b,h): 3-level db3 wavedec (ptwt reflect) -> per-band filter multiply ->
// waverec -> +residual -> LayerNorm over H.
// fp16x2-packed wavelet pipeline. Round-4 change: rounds 1-3 were register-
// starved (VGPR 40-64 vs ~85 live values) by launch_bounds occupancy demands,
// spilling the pipeline to scratch (round-3 WRITE = +21MB over output size).
// waves_per_eu(4,4) raises the VGPR budget to 128 so the pipeline lives in
// registers; occupancy 16 waves/CU (proven non-binding in rounds 0-2).

#define S_LEN 50
#define H_DIM 256
#define NPAIR 25

typedef _Float16 f16;
typedef __attribute__((ext_vector_type(2))) _Float16 f16x2;
typedef __attribute__((ext_vector_type(8))) _Float16 f16x8;

// d_ws layout (f16x2 elements): ft01 [10][256] | ft2 [8][256] | ft3 [14][256]
#define FT01_OFF 0
#define FT2_OFF (10 * H_DIM)
#define FT3_OFF (18 * H_DIM)
#define FT_BYTES (32 * H_DIM * 4)  // 32768

__device__ constexpr float DLO[6] = {
    0.035226291882100656f, -0.08544127388224149f, -0.13501102001039084f,
    0.4598775021193313f,   0.8068915093133388f,   0.3326705529509569f};
__device__ constexpr float DHI[6] = {
    -0.3326705529509569f,  0.8068915093133388f,  -0.4598775021193313f,
    -0.13501102001039084f, 0.08544127388224149f,  0.035226291882100656f};

static __device__ __forceinline__ f16x2 splat2(f16 v) {
  f16x2 r; r.x = v; r.y = v; return r;
}
static __device__ __forceinline__ f16x2 mk2(float a, float b) {
  f16x2 r; r.x = (f16)a; r.y = (f16)b; return r;
}

// Transpose+pack the learned filters into [l][h]-major f16x2 in ws.
__global__ void prep_filters(const float* __restrict__ f0,
                             const float* __restrict__ f1,
                             const float* __restrict__ f2,
                             const float* __restrict__ f3,
                             f16x2* __restrict__ ft) {
  const int h = threadIdx.x;
  const int b = blockIdx.x;
  if (b < 10) {  // (f0, f1) pair at tap l
    const int l = b;
    f16x2 v; v.x = (f16)f0[h * 10 + l]; v.y = (f16)f1[h * 10 + l];
    ft[FT01_OFF + l * H_DIM + h] = v;
  } else if (b < 18) {  // f2 taps (2k, 2k+1)
    const int k = b - 10;
    f16x2 v; v.x = (f16)f2[h * 16 + 2 * k]; v.y = (f16)f2[h * 16 + 2 * k + 1];
    ft[FT2_OFF + k * H_DIM + h] = v;
  } else {  // f3 taps (2k, 2k+1), last pair padded
    const int k = b - 18;
    f16x2 v;
    v.x = (f16)f3[h * 27 + 2 * k];
    v.y = (2 * k + 1 < 27) ? (f16)f3[h * 27 + 2 * k + 1] : (f16)0.f;
    ft[FT3_OFF + k * H_DIM + h] = v;
  }
}

// One analysis level, (lo,hi)-packed. out[i] = {cA[i], cD[i]}.
template <int N, class Get>
__device__ __forceinline__ void dwt_f16(const Get& X, f16x2* out) {
  constexpr int M = (N + 5) / 2;
#pragma unroll
  for (int i = 0; i < M; ++i) {
    f16x2 acc = mk2(0.f, 0.f);
#pragma unroll
    for (int j = 0; j < 6; ++j) {
      int idx = 2 * i + j - 4;
      idx = idx < 0 ? -idx : idx;
      idx = idx >= N ? 2 * N - 2 - idx : idx;
      acc += splat2(X(idx)) * mk2(DLO[5 - j], DHI[5 - j]);
    }
    out[i] = acc;
  }
}

// One synthesis level, adjacent-packed output: out2[t] = {rec[2t], rec[2t+1]}.
template <int T, class GLo, class GHi>
__device__ __forceinline__ void idwt_f16(const GLo& lo, const GHi& hi,
                                         f16x2* out2) {
#pragma unroll
  for (int t = 0; t < T / 2; ++t) {
    f16x2 acc = mk2(0.f, 0.f);
#pragma unroll
    for (int k = 0; k < 3; ++k) {
      acc += splat2(lo(t + k)) * mk2(DLO[2 * k + 1], DLO[2 * k]);
      acc += splat2(hi(t + k)) * mk2(DHI[2 * k + 1], DHI[2 * k]);
    }
    out2[t] = acc;
  }
  if constexpr (T & 1) {  // tail p = T-1 (even): taps {1,3,5}
    constexpr int t0 = T / 2;
    f16 s = (f16)0.f;
#pragma unroll
    for (int k = 0; k < 3; ++k)
      s += lo(t0 + k) * (f16)DLO[2 * k + 1] + hi(t0 + k) * (f16)DHI[2 * k + 1];
    f16x2 r; r.x = s; r.y = (f16)0.f;
    out2[t0] = r;
  }
}

template <bool USE_WS>
__global__ __launch_bounds__(256)
__attribute__((amdgpu_waves_per_eu(4, 4)))
void wavelet_ln_kernel(
    const float* __restrict__ in, const float* __restrict__ f0,
    const float* __restrict__ f1, const float* __restrict__ f2,
    const float* __restrict__ f3, const f16x2* __restrict__ ft,
    const float* __restrict__ gam, const float* __restrict__ bet,
    float* __restrict__ out) {
  __shared__ f16x2 slab[NPAIR * H_DIM];  // 25600 B
  const int tid = threadIdx.x;
  const size_t base = (size_t)blockIdx.x * (S_LEN * H_DIM);
  const float4* in4 = (const float4*)(in + base);

  // ---- phase 0: stage x as f16 pairs {x[2t],x[2t+1]} per h (float4 loads) --
  {
    f16x8* s8 = (f16x8*)slab;
#pragma unroll
    for (int i = 0; i < 7; ++i) {
      const int idx = i * 256 + tid;  // quad-of-pairs index in [0,1600)
      if (idx < NPAIR * 64) {
        const int t = idx >> 6, hq = idx & 63;
        const float4 a = in4[(2 * t) * 64 + hq];
        const float4 b = in4[(2 * t + 1) * 64 + hq];
        f16x8 o;
        o.s0 = (f16)a.x; o.s1 = (f16)b.x;
        o.s2 = (f16)a.y; o.s3 = (f16)b.y;
        o.s4 = (f16)a.z; o.s5 = (f16)b.z;
        o.s6 = (f16)a.w; o.s7 = (f16)b.w;
        s8[idx] = o;
      }
    }
  }
  __syncthreads();

  const int h = tid;

  // ---- phase 1: packed fp16 wavelet pipeline on own column ----
  {
    f16x2 xp[NPAIR];
#pragma unroll
    for (int t = 0; t < NPAIR; ++t) xp[t] = slab[t * H_DIM + h];  // 2-way, free

    f16x2 AD1[27];
    dwt_f16<50>([&](int s) -> f16 { return (s & 1) ? xp[s >> 1].y
                                                   : xp[s >> 1].x; }, AD1);
    f16x2 AD2[16];
    dwt_f16<27>([&](int s) -> f16 { return AD1[s].x; }, AD2);
    f16x2 AD3[10];
    dwt_f16<16>([&](int s) -> f16 { return AD2[s].x; }, AD3);

    // per-band learned filter multiply
    if constexpr (USE_WS) {
      // coalesced [l][h]-major packed loads (4 lines/wave-instr)
#pragma unroll
      for (int l = 0; l < 10; ++l) AD3[l] *= ft[FT01_OFF + l * H_DIM + h];
#pragma unroll
      for (int k = 0; k < 8; ++k) {
        const f16x2 c = ft[FT2_OFF + k * H_DIM + h];
        AD2[2 * k].y *= c.x;
        AD2[2 * k + 1].y *= c.y;
      }
#pragma unroll
      for (int k = 0; k < 14; ++k) {
        const f16x2 c = ft[FT3_OFF + k * H_DIM + h];
        AD1[2 * k].y *= c.x;
        if (2 * k + 1 < 27) AD1[2 * k + 1].y *= c.y;
      }
    } else {  // fallback: direct (gathered) loads
      const float* f0h = f0 + h * 10;
      const float* f1h = f1 + h * 10;
#pragma unroll
      for (int l = 0; l < 10; ++l) AD3[l] *= mk2(f0h[l], f1h[l]);
      const float* f2h = f2 + h * 16;
#pragma unroll
      for (int l = 0; l < 16; ++l) AD2[l].y *= (f16)f2h[l];
      const float* f3h = f3 + h * 27;
#pragma unroll
      for (int l = 0; l < 27; ++l) AD1[l].y *= (f16)f3h[l];
    }

    // synthesis
    f16x2 rr2[8];
    idwt_f16<16>([&](int s) -> f16 { return AD3[s].x; },
                 [&](int s) -> f16 { return AD3[s].y; }, rr2);
    f16x2 rr1[14];
    idwt_f16<27>([&](int s) -> f16 { return (s & 1) ? rr2[s >> 1].y
                                                    : rr2[s >> 1].x; },
                 [&](int s) -> f16 { return AD2[s].y; }, rr1);

    // final level fused: write rec pairs over the slab (column-private)
    auto lo = [&](int s) -> f16 { return (s & 1) ? rr1[s >> 1].y
                                                 : rr1[s >> 1].x; };
    auto hi = [&](int s) -> f16 { return AD1[s].y; };
#pragma unroll
    for (int t = 0; t < NPAIR; ++t) {
      f16x2 acc = mk2(0.f, 0.f);
#pragma unroll
      for (int k = 0; k < 3; ++k) {
        acc += splat2(lo(t + k)) * mk2(DLO[2 * k + 1], DLO[2 * k]);
        acc += splat2(hi(t + k)) * mk2(DHI[2 * k + 1], DHI[2 * k]);
      }
      slab[t * H_DIM + h] = acc;
    }
  }
  __syncthreads();

  // ---- phase 2: LN over H, two s-rows per iteration per wave ----
  const int lane = tid & 63;
  const int wv = tid >> 6;
  const float4 g4 = ((const float4*)gam)[lane];
  const float4 b4 = ((const float4*)bet)[lane];
  float4* out4 = (float4*)(out + base);
  const f16x8* s8 = (const f16x8*)slab;
  for (int t = wv; t < NPAIR; t += 4) {
    const f16x8 r8 = s8[t * 64 + lane];           // rec pairs, 4 h's
    const float4 xa = in4[(2 * t) * 64 + lane];   // exact x, L2/L3-hit
    const float4 xb = in4[(2 * t + 1) * 64 + lane];
    const float ye0 = xa.x + (float)r8.s0, yo0 = xb.x + (float)r8.s1;
    const float ye1 = xa.y + (float)r8.s2, yo1 = xb.y + (float)r8.s3;
    const float ye2 = xa.z + (float)r8.s4, yo2 = xb.z + (float)r8.s5;
    const float ye3 = xa.w + (float)r8.s6, yo3 = xb.w + (float)r8.s7;
    float se = ye0 + ye1 + ye2 + ye3;
    float so = yo0 + yo1 + yo2 + yo3;
    float qe = ye0 * ye0 + ye1 * ye1 + ye2 * ye2 + ye3 * ye3;
    float qo = yo0 * yo0 + yo1 * yo1 + yo2 * yo2 + yo3 * yo3;
#pragma unroll
    for (int o = 32; o >= 1; o >>= 1) {
      se += __shfl_xor(se, o);
      so += __shfl_xor(so, o);
      qe += __shfl_xor(qe, o);
      qo += __shfl_xor(qo, o);
    }
    const float mue = se * (1.0f / H_DIM), muo = so * (1.0f / H_DIM);
    const float rse =
        rsqrtf(fmaxf(qe * (1.0f / H_DIM) - mue * mue, 0.0f) + 1e-12f);
    const float rso =
        rsqrtf(fmaxf(qo * (1.0f / H_DIM) - muo * muo, 0.0f) + 1e-12f);
    float4 oe, oo;
    oe.x = (ye0 - mue) * rse * g4.x + b4.x;
    oe.y = (ye1 - mue) * rse * g4.y + b4.y;
    oe.z = (ye2 - mue) * rse * g4.z + b4.z;
    oe.w = (ye3 - mue) * rse * g4.w + b4.w;
    oo.x = (yo0 - muo) * rso * g4.x + b4.x;
    oo.y = (yo1 - muo) * rso * g4.y + b4.y;
    oo.z = (yo2 - muo) * rso * g4.z + b4.z;
    oo.w = (yo3 - muo) * rso * g4.w + b4.w;
    out4[(2 * t) * 64 + lane] = oe;       // dense coalesced row stores
    out4[(2 * t + 1) * 64 + lane] = oo;
  }
}

extern "C" void kernel_launch(void* const* d_in, const int* in_sizes, int n_in,
                              void* d_out, int out_size, void* d_ws,
                              size_t ws_size, hipStream_t stream) {
  // setup_inputs() dict order: input_tensor, ln_gamma, ln_beta, filt0..filt3
  const float* in = (const float*)d_in[0];
  const float* gam = (const float*)d_in[1];
  const float* bet = (const float*)d_in[2];
  const float* f0 = (const float*)d_in[3];
  const float* f1 = (const float*)d_in[4];
  const float* f2 = (const float*)d_in[5];
  const float* f3 = (const float*)d_in[6];
  float* out = (float*)d_out;

  if (ws_size >= (size_t)FT_BYTES) {
    f16x2* ft = (f16x2*)d_ws;
    prep_filters<<<32, 256, 0, stream>>>(f0, f1, f2, f3, ft);
    wavelet_ln_kernel<true><<<4096, 256, 0, stream>>>(in, f0, f1, f2, f3, ft,
                                                      gam, bet, out);
  } else {
    wavelet_ln_kernel<false><<<4096, 256, 0, stream>>>(
        in, f0, f1, f2, f3, nullptr, gam, bet, out);
  }
}

// Round 6
// 98.592 us; speedup vs baseline: 1.2844x; 1.1398x over previous
//
#include <hip/hip_runtime.h>
#include <math.h>

// WaveletLayer: (B=4096, S=50, H=256) fp32.
// Per (b,h): 3-level db3 wavedec (ptwt reflect) -> per-band filter multiply ->
// waverec -> +residual -> LayerNorm over H.
// fp16x2-packed wavelet pipeline. Round-5 changes:
//  (1) waves_per_eu(5,8): VGPR cap 102 (no spill; r4 proved 52 suffices) while
//      allowing 6 blocks/CU (LDS 153.6/160 KiB) -> cross-block phase overlap.
//      r3 had residency+spills, r4 had no-spills+low residency; this has both.
//  (2) slab holds y = x + rec (xp already in regs) instead of rec -> phase 2
//      is pure LDS+LN, no global x re-read on the critical path.

#define S_LEN 50
#define H_DIM 256
#define NPAIR 25

typedef _Float16 f16;
typedef __attribute__((ext_vector_type(2))) _Float16 f16x2;
typedef __attribute__((ext_vector_type(8))) _Float16 f16x8;

// d_ws layout (f16x2 elements): ft01 [10][256] | ft2 [8][256] | ft3 [14][256]
#define FT01_OFF 0
#define FT2_OFF (10 * H_DIM)
#define FT3_OFF (18 * H_DIM)
#define FT_BYTES (32 * H_DIM * 4)  // 32768

__device__ constexpr float DLO[6] = {
    0.035226291882100656f, -0.08544127388224149f, -0.13501102001039084f,
    0.4598775021193313f,   0.8068915093133388f,   0.3326705529509569f};
__device__ constexpr float DHI[6] = {
    -0.3326705529509569f,  0.8068915093133388f,  -0.4598775021193313f,
    -0.13501102001039084f, 0.08544127388224149f,  0.035226291882100656f};

static __device__ __forceinline__ f16x2 splat2(f16 v) {
  f16x2 r; r.x = v; r.y = v; return r;
}
static __device__ __forceinline__ f16x2 mk2(float a, float b) {
  f16x2 r; r.x = (f16)a; r.y = (f16)b; return r;
}

// Transpose+pack the learned filters into [l][h]-major f16x2 in ws.
__global__ void prep_filters(const float* __restrict__ f0,
                             const float* __restrict__ f1,
                             const float* __restrict__ f2,
                             const float* __restrict__ f3,
                             f16x2* __restrict__ ft) {
  const int h = threadIdx.x;
  const int b = blockIdx.x;
  if (b < 10) {  // (f0, f1) pair at tap l
    const int l = b;
    f16x2 v; v.x = (f16)f0[h * 10 + l]; v.y = (f16)f1[h * 10 + l];
    ft[FT01_OFF + l * H_DIM + h] = v;
  } else if (b < 18) {  // f2 taps (2k, 2k+1)
    const int k = b - 10;
    f16x2 v; v.x = (f16)f2[h * 16 + 2 * k]; v.y = (f16)f2[h * 16 + 2 * k + 1];
    ft[FT2_OFF + k * H_DIM + h] = v;
  } else {  // f3 taps (2k, 2k+1), last pair padded
    const int k = b - 18;
    f16x2 v;
    v.x = (f16)f3[h * 27 + 2 * k];
    v.y = (2 * k + 1 < 27) ? (f16)f3[h * 27 + 2 * k + 1] : (f16)0.f;
    ft[FT3_OFF + k * H_DIM + h] = v;
  }
}

// One analysis level, (lo,hi)-packed. out[i] = {cA[i], cD[i]}.
template <int N, class Get>
__device__ __forceinline__ void dwt_f16(const Get& X, f16x2* out) {
  constexpr int M = (N + 5) / 2;
#pragma unroll
  for (int i = 0; i < M; ++i) {
    f16x2 acc = mk2(0.f, 0.f);
#pragma unroll
    for (int j = 0; j < 6; ++j) {
      int idx = 2 * i + j - 4;
      idx = idx < 0 ? -idx : idx;
      idx = idx >= N ? 2 * N - 2 - idx : idx;
      acc += splat2(X(idx)) * mk2(DLO[5 - j], DHI[5 - j]);
    }
    out[i] = acc;
  }
}

// One synthesis level, adjacent-packed output: out2[t] = {rec[2t], rec[2t+1]}.
template <int T, class GLo, class GHi>
__device__ __forceinline__ void idwt_f16(const GLo& lo, const GHi& hi,
                                         f16x2* out2) {
#pragma unroll
  for (int t = 0; t < T / 2; ++t) {
    f16x2 acc = mk2(0.f, 0.f);
#pragma unroll
    for (int k = 0; k < 3; ++k) {
      acc += splat2(lo(t + k)) * mk2(DLO[2 * k + 1], DLO[2 * k]);
      acc += splat2(hi(t + k)) * mk2(DHI[2 * k + 1], DHI[2 * k]);
    }
    out2[t] = acc;
  }
  if constexpr (T & 1) {  // tail p = T-1 (even): taps {1,3,5}
    constexpr int t0 = T / 2;
    f16 s = (f16)0.f;
#pragma unroll
    for (int k = 0; k < 3; ++k)
      s += lo(t0 + k) * (f16)DLO[2 * k + 1] + hi(t0 + k) * (f16)DHI[2 * k + 1];
    f16x2 r; r.x = s; r.y = (f16)0.f;
    out2[t0] = r;
  }
}

template <bool USE_WS>
__global__ __launch_bounds__(256)
__attribute__((amdgpu_waves_per_eu(5, 8)))
void wavelet_ln_kernel(
    const float* __restrict__ in, const float* __restrict__ f0,
    const float* __restrict__ f1, const float* __restrict__ f2,
    const float* __restrict__ f3, const f16x2* __restrict__ ft,
    const float* __restrict__ gam, const float* __restrict__ bet,
    float* __restrict__ out) {
  __shared__ f16x2 slab[NPAIR * H_DIM];  // 25600 B -> up to 6 blocks/CU
  const int tid = threadIdx.x;
  const size_t base = (size_t)blockIdx.x * (S_LEN * H_DIM);
  const float4* in4 = (const float4*)(in + base);

  // ---- phase 0: stage x as f16 pairs {x[2t],x[2t+1]} per h (float4 loads) --
  {
    f16x8* s8 = (f16x8*)slab;
#pragma unroll
    for (int i = 0; i < 7; ++i) {
      const int idx = i * 256 + tid;  // quad-of-pairs index in [0,1600)
      if (idx < NPAIR * 64) {
        const int t = idx >> 6, hq = idx & 63;
        const float4 a = in4[(2 * t) * 64 + hq];
        const float4 b = in4[(2 * t + 1) * 64 + hq];
        f16x8 o;
        o.s0 = (f16)a.x; o.s1 = (f16)b.x;
        o.s2 = (f16)a.y; o.s3 = (f16)b.y;
        o.s4 = (f16)a.z; o.s5 = (f16)b.z;
        o.s6 = (f16)a.w; o.s7 = (f16)b.w;
        s8[idx] = o;
      }
    }
  }
  __syncthreads();

  const int h = tid;

  // ---- phase 1: packed fp16 wavelet pipeline on own column ----
  {
    f16x2 xp[NPAIR];
#pragma unroll
    for (int t = 0; t < NPAIR; ++t) xp[t] = slab[t * H_DIM + h];  // 2-way, free

    f16x2 AD1[27];
    dwt_f16<50>([&](int s) -> f16 { return (s & 1) ? xp[s >> 1].y
                                                   : xp[s >> 1].x; }, AD1);
    f16x2 AD2[16];
    dwt_f16<27>([&](int s) -> f16 { return AD1[s].x; }, AD2);
    f16x2 AD3[10];
    dwt_f16<16>([&](int s) -> f16 { return AD2[s].x; }, AD3);

    // per-band learned filter multiply
    if constexpr (USE_WS) {
      // coalesced [l][h]-major packed loads (4 lines/wave-instr)
#pragma unroll
      for (int l = 0; l < 10; ++l) AD3[l] *= ft[FT01_OFF + l * H_DIM + h];
#pragma unroll
      for (int k = 0; k < 8; ++k) {
        const f16x2 c = ft[FT2_OFF + k * H_DIM + h];
        AD2[2 * k].y *= c.x;
        AD2[2 * k + 1].y *= c.y;
      }
#pragma unroll
      for (int k = 0; k < 14; ++k) {
        const f16x2 c = ft[FT3_OFF + k * H_DIM + h];
        AD1[2 * k].y *= c.x;
        if (2 * k + 1 < 27) AD1[2 * k + 1].y *= c.y;
      }
    } else {  // fallback: direct (gathered) loads
      const float* f0h = f0 + h * 10;
      const float* f1h = f1 + h * 10;
#pragma unroll
      for (int l = 0; l < 10; ++l) AD3[l] *= mk2(f0h[l], f1h[l]);
      const float* f2h = f2 + h * 16;
#pragma unroll
      for (int l = 0; l < 16; ++l) AD2[l].y *= (f16)f2h[l];
      const float* f3h = f3 + h * 27;
#pragma unroll
      for (int l = 0; l < 27; ++l) AD1[l].y *= (f16)f3h[l];
    }

    // synthesis
    f16x2 rr2[8];
    idwt_f16<16>([&](int s) -> f16 { return AD3[s].x; },
                 [&](int s) -> f16 { return AD3[s].y; }, rr2);
    f16x2 rr1[14];
    idwt_f16<27>([&](int s) -> f16 { return (s & 1) ? rr2[s >> 1].y
                                                    : rr2[s >> 1].x; },
                 [&](int s) -> f16 { return AD2[s].y; }, rr1);

    // final level fused with residual: slab <- y = x + rec (column-private)
    auto lo = [&](int s) -> f16 { return (s & 1) ? rr1[s >> 1].y
                                                 : rr1[s >> 1].x; };
    auto hi = [&](int s) -> f16 { return AD1[s].y; };
#pragma unroll
    for (int t = 0; t < NPAIR; ++t) {
      f16x2 acc = mk2(0.f, 0.f);
#pragma unroll
      for (int k = 0; k < 3; ++k) {
        acc += splat2(lo(t + k)) * mk2(DLO[2 * k + 1], DLO[2 * k]);
        acc += splat2(hi(t + k)) * mk2(DHI[2 * k + 1], DHI[2 * k]);
      }
      slab[t * H_DIM + h] = xp[t] + acc;  // y pairs
    }
  }
  __syncthreads();

  // ---- phase 2: LN over H from slab only, two s-rows per iteration ----
  const int lane = tid & 63;
  const int wv = tid >> 6;
  const float4 g4 = ((const float4*)gam)[lane];
  const float4 b4 = ((const float4*)bet)[lane];
  float4* out4 = (float4*)(out + base);
  const f16x8* s8 = (const f16x8*)slab;
  for (int t = wv; t < NPAIR; t += 4) {
    const f16x8 r8 = s8[t * 64 + lane];  // y pairs, 4 h's
    const float ye0 = (float)r8.s0, yo0 = (float)r8.s1;
    const float ye1 = (float)r8.s2, yo1 = (float)r8.s3;
    const float ye2 = (float)r8.s4, yo2 = (float)r8.s5;
    const float ye3 = (float)r8.s6, yo3 = (float)r8.s7;
    float se = ye0 + ye1 + ye2 + ye3;
    float so = yo0 + yo1 + yo2 + yo3;
    float qe = ye0 * ye0 + ye1 * ye1 + ye2 * ye2 + ye3 * ye3;
    float qo = yo0 * yo0 + yo1 * yo1 + yo2 * yo2 + yo3 * yo3;
#pragma unroll
    for (int o = 32; o >= 1; o >>= 1) {
      se += __shfl_xor(se, o);
      so += __shfl_xor(so, o);
      qe += __shfl_xor(qe, o);
      qo += __shfl_xor(qo, o);
    }
    const float mue = se * (1.0f / H_DIM), muo = so * (1.0f / H_DIM);
    const float rse =
        rsqrtf(fmaxf(qe * (1.0f / H_DIM) - mue * mue, 0.0f) + 1e-12f);
    const float rso =
        rsqrtf(fmaxf(qo * (1.0f / H_DIM) - muo * muo, 0.0f) + 1e-12f);
    float4 oe, oo;
    oe.x = (ye0 - mue) * rse * g4.x + b4.x;
    oe.y = (ye1 - mue) * rse * g4.y + b4.y;
    oe.z = (ye2 - mue) * rse * g4.z + b4.z;
    oe.w = (ye3 - mue) * rse * g4.w + b4.w;
    oo.x = (yo0 - muo) * rso * g4.x + b4.x;
    oo.y = (yo1 - muo) * rso * g4.y + b4.y;
    oo.z = (yo2 - muo) * rso * g4.z + b4.z;
    oo.w = (yo3 - muo) * rso * g4.w + b4.w;
    out4[(2 * t) * 64 + lane] = oe;       // dense coalesced row stores
    out4[(2 * t + 1) * 64 + lane] = oo;
  }
}

extern "C" void kernel_launch(void* const* d_in, const int* in_sizes, int n_in,
                              void* d_out, int out_size, void* d_ws,
                              size_t ws_size, hipStream_t stream) {
  // setup_inputs() dict order: input_tensor, ln_gamma, ln_beta, filt0..filt3
  const float* in = (const float*)d_in[0];
  const float* gam = (const float*)d_in[1];
  const float* bet = (const float*)d_in[2];
  const float* f0 = (const float*)d_in[3];
  const float* f1 = (const float*)d_in[4];
  const float* f2 = (const float*)d_in[5];
  const float* f3 = (const float*)d_in[6];
  float* out = (float*)d_out;

  if (ws_size >= (size_t)FT_BYTES) {
    f16x2* ft = (f16x2*)d_ws;
    prep_filters<<<32, 256, 0, stream>>>(f0, f1, f2, f3, ft);
    wavelet_ln_kernel<true><<<4096, 256, 0, stream>>>(in, f0, f1, f2, f3, ft,
                                                      gam, bet, out);
  } else {
    wavelet_ln_kernel<false><<<4096, 256, 0, stream>>>(
        in, f0, f1, f2, f3, nullptr, gam, bet, out);
  }
}